// Round 10
// baseline (411.946 us; speedup 1.0000x reference)
//
#include <hip/hip_runtime.h>

#define N_ROWS 65536
#define K_CODES 4096
#define D_DIM 256
#define MARGIN_BF 4.5e-5f

typedef __attribute__((ext_vector_type(8))) _Float16 f16x8;
typedef __attribute__((ext_vector_type(4))) float f32x4;

typedef __attribute__((address_space(1))) unsigned int g_u32;
typedef __attribute__((address_space(3))) unsigned int l_u32;
// async global->LDS, 16B per lane; LDS dest = wave-uniform base + lane*16
#define GLOAD16(gp, lp) __builtin_amdgcn_global_load_lds((g_u32*)(gp), (l_u32*)(lp), 16, 0, 0)

// ---------------- ws layout ----------------
// [0]        float  rownorm[65536]      256 KB
// [262144]   float  cvec[4096]           16 KB
// [278528]   ushort emb_perm[4096*256]    2 MB   (f16 x4096, chunk-linear)
// [2375680]  int    flagcnt
// [2375936]  int    flaglist[65536]     256 KB
// [2638080]  u64    rescored[65536]     512 KB
// [3162368]  double partials[2048]       16 KB
// z_perm (33.5 MB, f16 fragment-linear) lives in d_out as scratch;
// writeback_kernel fully overwrites d_out afterwards (deterministic each replay).

union f16u { _Float16 h; unsigned short u; };

static __device__ __forceinline__ unsigned int pack2(float a, float b) {
    f16u x, y; x.h = (_Float16)a; y.h = (_Float16)b;
    return (unsigned)x.u | ((unsigned)y.u << 16);
}

// ---------------- r2-verified norm chain (verbatim body, block-offset) ----------------
static __device__ __forceinline__ void norm_body(const float* __restrict__ src,
                                                 float* __restrict__ dst, int bi, int tid) {
    int row = bi * 64 + (tid >> 2);
    int q = tid & 3;
    const float* p = src + (size_t)row * D_DIM;
    double acc = 0.0;
#pragma unroll 4
    for (int it = 0; it < 16; ++it) {
        float4 v = *(const float4*)&p[(q + 4 * it) * 4];
        float a = v.x * v.x, b = v.y * v.y, c = v.z * v.z, d = v.w * v.w;
        acc += (double)a; acc += (double)b; acc += (double)c; acc += (double)d;
    }
    acc += __shfl_xor(acc, 1);
    acc += __shfl_xor(acc, 2);
    if (q == 0) dst[row] = (float)acc;
}

// ---------------- emb -> f16(x4096) chunk-linear  +  fused emb-norm ----------------
// unit gid = ((c2*2 + s)*2 + cf)*64 + lane, c2 = kt*8+ds8 (512 chunks of 4KB per strip-pair)
// holds emb[kt*64 + s*32 + cf*16 + (lane&15)][ds8*32 + (lane>>4)*8 + 0..7] * 4096
__global__ __launch_bounds__(256) void cvt_emb_kernel(const float* __restrict__ emb,
                                                      unsigned short* __restrict__ emb_perm,
                                                      float* __restrict__ cvec,
                                                      int* __restrict__ flagcnt) {
    if (blockIdx.x >= 512) {
        if (blockIdx.x == 512 && threadIdx.x == 0) *flagcnt = 0;
        norm_body(emb, cvec, blockIdx.x - 512, threadIdx.x);
        return;
    }
    int gid = blockIdx.x * 256 + threadIdx.x;     // 131072 units
    int lane = gid & 63;
    int cf = (gid >> 6) & 1;
    int s = (gid >> 7) & 1;
    int c2 = gid >> 8;
    int kt = c2 >> 3, ds8 = c2 & 7;
    int code = kt * 64 + s * 32 + cf * 16 + (lane & 15);
    int d0 = ds8 * 32 + (lane >> 4) * 8;
    const float* p = emb + (size_t)code * D_DIM + d0;
    float4 v0 = *(const float4*)p;
    float4 v1 = *(const float4*)(p + 4);
    uint4 o;
    o.x = pack2(v0.x * 4096.0f, v0.y * 4096.0f);
    o.y = pack2(v0.z * 4096.0f, v0.w * 4096.0f);
    o.z = pack2(v1.x * 4096.0f, v1.y * 4096.0f);
    o.w = pack2(v1.z * 4096.0f, v1.w * 4096.0f);
    *(uint4*)((char*)emb_perm + (size_t)gid * 16) = o;
}

// ---------------- z -> f16 fragment-linear  +  fused z-norm + rescored clear ----------------
// ft = rb*2048 + p*1024 + ds8*128 + rf*64 + lane
// holds z[rb*64 + p*32 + rf*16 + (lane&15)][ds8*32 + (lane>>4)*8 + 0..7]
__global__ __launch_bounds__(256) void cvt_z_kernel(const float* __restrict__ z,
                                                    unsigned short* __restrict__ z_perm,
                                                    float* __restrict__ rownorm,
                                                    unsigned long long* __restrict__ rescored) {
    if (blockIdx.x >= 8192) {
        norm_body(z, rownorm, blockIdx.x - 8192, threadIdx.x);
        return;
    }
    if (blockIdx.x < 256) rescored[blockIdx.x * 256 + threadIdx.x] = ~0ull;
    int ft = blockIdx.x * 256 + threadIdx.x;      // 2097152 frags
    int lane = ft & 63;
    int rf = (ft >> 6) & 1;
    int ds8 = (ft >> 7) & 7;
    int pp = (ft >> 10) & 1;
    int rb = ft >> 11;
    int row = rb * 64 + pp * 32 + rf * 16 + (lane & 15);
    int d0 = ds8 * 32 + (lane >> 4) * 8;
    const float* p = z + (size_t)row * D_DIM + d0;
    float4 v0 = *(const float4*)p;
    float4 v1 = *(const float4*)(p + 4);
    uint4 o;
    o.x = pack2(v0.x, v0.y);
    o.y = pack2(v0.z, v0.w);
    o.z = pack2(v1.x, v1.y);
    o.w = pack2(v1.z, v1.w);
    *(uint4*)((char*)z_perm + (size_t)ft * 16) = o;
}

// ---------------- phase B: 4-wave barrier-free f16 MFMA argmin, A in 64 VGPR ----------------
// wave w: rows (w>>1)*32..+32 (A in regs), code strip (w&1): [kt*64+(w&1)*32, +32), kt 0..63.
// Private 4-slot 2KB LDS ring, staged 3 ahead; vmcnt(4) + b-reg prefetch. No K-loop barriers.
__global__ __launch_bounds__(256, 3) void phaseB_kernel(
        const unsigned short* __restrict__ z_perm, const unsigned short* __restrict__ emb_perm,
        const float* __restrict__ cvec, float* __restrict__ out_idx,
        int* __restrict__ flagcnt, int* __restrict__ flaglist) {
    __shared__ unsigned short ebuf[4][4][1024];   // [wave][slot][2KB] = 32 KB

    const int tid = threadIdx.x;
    const int lane = tid & 63;
    const int w = tid >> 6;
    const int s = w & 1;          // code strip
    const int pp = w >> 1;        // row pair
    const int l15 = lane & 15, l4 = lane >> 4;
    const int rb = blockIdx.x;

    // ---- A (32 rows) into registers: 16 frags = 64 VGPR ----
    f16x8 A[8][2];
    {
        const char* zsrc = (const char*)z_perm + ((size_t)(rb * 2 + pp) * 16) * 1024 + lane * 16;
#pragma unroll
        for (int d8 = 0; d8 < 8; ++d8)
#pragma unroll
            for (int rf = 0; rf < 2; ++rf)
                A[d8][rf] = *(const f16x8*)(zsrc + (d8 * 2 + rf) * 1024);
    }

    // ---- prologue: stage chunks 0..2 into slots 0..2 ----
    const char* ebase = (const char*)emb_perm + s * 2048 + lane * 16;
#pragma unroll
    for (int c = 0; c < 3; ++c) {
        GLOAD16(ebase + c * 4096, &ebuf[w][c][0]);
        GLOAD16(ebase + c * 4096 + 1024, &ebuf[w][c][512]);
    }

    float m1[8], m2[8];
    int i1[8];
#pragma unroll
    for (int t = 0; t < 8; ++t) { m1[t] = 3.4e38f; m2[t] = 3.4e38f; i1[t] = 0; }

    // wait A + chunk0 (A oldest in FIFO; retire to 4 leaves chunks 1,2 in flight)
    asm volatile("s_waitcnt vmcnt(4)" ::: "memory");
    f16x8 bc0 = *(const f16x8*)((const char*)&ebuf[w][0][0] + lane * 16);
    f16x8 bc1 = *(const f16x8*)((const char*)&ebuf[w][0][0] + 1024 + lane * 16);

    const char* sp = ebase + 3 * 4096;   // global addr of chunk c+3 at kt=0
    f32x4 acc[2][2];

    for (int kt = 0; kt < 64; ++kt) {
        const int kb = kt * 64 + s * 32;
        float ck0 = cvec[kb + l15];
        float ck1 = cvec[kb + 16 + l15];
#pragma unroll
        for (int rf = 0; rf < 2; ++rf)
#pragma unroll
            for (int cf = 0; cf < 2; ++cf) acc[rf][cf] = (f32x4){0.f, 0.f, 0.f, 0.f};
        const int wrap = (kt == 63) ? (512 * 4096) : 0;   // tail re-stages chunks 0..2 (dead slots)
#pragma unroll
        for (int d8 = 0; d8 < 8; ++d8) {
            // stage chunk c+3 into slot (d8+3)&3 (== slot(c-1); its reads retired at iter c-2)
            {
                const char* g = sp + d8 * 4096 - ((d8 >= 5) ? wrap : 0);
                GLOAD16(g, &ebuf[w][(d8 + 3) & 3][0]);
                GLOAD16(g + 1024, &ebuf[w][(d8 + 3) & 3][512]);
            }
            // retire through chunk c+1 (outstanding c+1..c+3 = 6 -> <=4)
            asm volatile("s_waitcnt vmcnt(4)" ::: "memory");
            const char* nb = (const char*)&ebuf[w][(d8 + 1) & 3][0];
            f16x8 bn0 = *(const f16x8*)(nb + lane * 16);
            f16x8 bn1 = *(const f16x8*)(nb + 1024 + lane * 16);
#pragma unroll
            for (int rf = 0; rf < 2; ++rf) {
                acc[rf][0] = __builtin_amdgcn_mfma_f32_16x16x32_f16(A[d8][rf], bc0, acc[rf][0], 0, 0, 0);
                acc[rf][1] = __builtin_amdgcn_mfma_f32_16x16x32_f16(A[d8][rf], bc1, acc[rf][1], 0, 0, 0);
            }
            bc0 = bn0; bc1 = bn1;
        }
        sp += 8 * 4096;

        // ---- epilogue: top-2 over this kt's 32 strip-codes ----
#pragma unroll
        for (int cf = 0; cf < 2; ++cf) {
            float ck = cf ? ck1 : ck0;
            int codeg = kb + cf * 16 + l15;
#pragma unroll
            for (int rf = 0; rf < 2; ++rf)
#pragma unroll
                for (int j = 0; j < 4; ++j) {
                    // acc = z.(4096 e); -2*dot = acc * -2^-11 (exact scale)
                    float d = fmaf(-4.8828125e-4f, acc[rf][cf][j], ck);
                    const int t = rf * 4 + j;
                    bool lt = d < m1[t];
                    m2[t] = __builtin_amdgcn_fmed3f(d, m1[t], m2[t]);  // == min(m2,max(d,m1))
                    i1[t] = lt ? codeg : i1[t];
                    m1[t] = fminf(m1[t], d);
                }
        }
    }

    // ---- per-wave merge across the 16 column-lanes ----
    __syncthreads();                       // all waves done; ebuf reusable
    float* m1s = (float*)&ebuf[0][0][0];   // [4][32]
    float* m2s = m1s + 128;                // [4][32]
    int*   i1s = (int*)(m2s + 128);        // [4][32]
#pragma unroll
    for (int t = 0; t < 8; ++t) {
        float a1 = m1[t], a2 = m2[t];
        int ai = i1[t];
        for (int msk = 8; msk >= 1; msk >>= 1) {
            float b1 = __shfl_xor(a1, msk);
            float b2 = __shfl_xor(a2, msk);
            int   bi = __shfl_xor(ai, msk);
            float hi = fmaxf(a1, b1);
            a2 = fminf(fminf(a2, b2), hi);
            if (b1 < a1 || (b1 == a1 && bi < ai)) { a1 = b1; ai = bi; }
        }
        if (l15 == 0) {
            int rloc = (t >> 2) * 16 + l4 * 4 + (t & 3);   // rf*16 + l4*4 + j, 0..31
            m1s[w * 32 + rloc] = a1;
            m2s[w * 32 + rloc] = a2;
            i1s[w * 32 + rloc] = ai;
        }
    }
    __syncthreads();

    // ---- cross-wave merge: waves (2h, 2h+1) hold disjoint strips for rows h*32.. ----
    if (tid < 64) {
        int h = tid >> 5, r = tid & 31;
        float b1 = 3.4e38f, b2 = 3.4e38f;
        int bi = 0;
#pragma unroll
        for (int u = 0; u < 2; ++u) {
            int ww = h * 2 + u;
            float c1 = m1s[ww * 32 + r];
            float c2 = m2s[ww * 32 + r];
            int ci = i1s[ww * 32 + r];
            float hi2 = fmaxf(b1, c1);
            b2 = fminf(fminf(b2, c2), hi2);
            if (c1 < b1 || (c1 == b1 && ci < bi)) { b1 = c1; bi = ci; }
        }
        int rowg = rb * 64 + h * 32 + r;
        out_idx[rowg] = (float)bi;
        if (b2 - b1 < MARGIN_BF) {
            int pz = atomicAdd(flagcnt, 1);
            flaglist[pz] = rowg;
        }
    }
}

// ---------------- exact f32 rescore: 4 codes/thread (chain bit-identical to r2) ----------------
__global__ __launch_bounds__(256) void rescore_kernel(
        const float* __restrict__ z, const float* __restrict__ emb,
        const float* __restrict__ rownorm, const float* __restrict__ cvec,
        const int* __restrict__ flagcnt, const int* __restrict__ flaglist,
        unsigned long long* __restrict__ rescored) {
    __shared__ float zs[16][256];
    __shared__ float sa[16];
    __shared__ int srow[16];
    const int tid = threadIdx.x;
    const int cnt = *flagcnt;
    const int nu = ((cnt + 15) >> 4) << 2;   // ceil(cnt/16) row-groups x 4 code-splits
    for (int uu = blockIdx.x; uu < nu; uu += gridDim.x) {
        int rg = uu >> 2, ks = uu & 3;
        __syncthreads();                      // previous unit done with zs/srow
        if (tid < 16) {
            int fi = rg * 16 + tid;
            int row = flaglist[fi < cnt ? fi : 0];   // padding = a real flagged row
            srow[tid] = row;
            sa[tid] = rownorm[row];
        }
        __syncthreads();
#pragma unroll
        for (int i = 0; i < 4; ++i) {
            int u = i * 256 + tid;            // 1024 float4 units
            int r = u >> 6, d4 = u & 63;
            *(float4*)&zs[r][d4 * 4] = *(const float4*)&z[(size_t)srow[r] * D_DIM + d4 * 4];
        }
        __syncthreads();

        const int c0 = ks * 1024 + tid;       // codes c0 + {0,256,512,768}
        float acc[16][4];
#pragma unroll
        for (int r = 0; r < 16; ++r)
#pragma unroll
            for (int j = 0; j < 4; ++j) acc[r][j] = 0.f;

        for (int ch = 0; ch < 8; ++ch) {      // 32 d per chunk, d ascending overall
#pragma unroll
            for (int q = 0; q < 8; ++q) {
                float4 e0 = *(const float4*)&emb[(size_t)(c0      ) * D_DIM + ch * 32 + q * 4];
                float4 e1 = *(const float4*)&emb[(size_t)(c0 + 256) * D_DIM + ch * 32 + q * 4];
                float4 e2 = *(const float4*)&emb[(size_t)(c0 + 512) * D_DIM + ch * 32 + q * 4];
                float4 e3 = *(const float4*)&emb[(size_t)(c0 + 768) * D_DIM + ch * 32 + q * 4];
#pragma unroll
                for (int r = 0; r < 16; ++r) {
                    float4 zf = *(const float4*)&zs[r][ch * 32 + q * 4];   // LDS broadcast
                    acc[r][0] = fmaf(zf.x, e0.x, acc[r][0]);
                    acc[r][0] = fmaf(zf.y, e0.y, acc[r][0]);
                    acc[r][0] = fmaf(zf.z, e0.z, acc[r][0]);
                    acc[r][0] = fmaf(zf.w, e0.w, acc[r][0]);
                    acc[r][1] = fmaf(zf.x, e1.x, acc[r][1]);
                    acc[r][1] = fmaf(zf.y, e1.y, acc[r][1]);
                    acc[r][1] = fmaf(zf.z, e1.z, acc[r][1]);
                    acc[r][1] = fmaf(zf.w, e1.w, acc[r][1]);
                    acc[r][2] = fmaf(zf.x, e2.x, acc[r][2]);
                    acc[r][2] = fmaf(zf.y, e2.y, acc[r][2]);
                    acc[r][2] = fmaf(zf.z, e2.z, acc[r][2]);
                    acc[r][2] = fmaf(zf.w, e2.w, acc[r][2]);
                    acc[r][3] = fmaf(zf.x, e3.x, acc[r][3]);
                    acc[r][3] = fmaf(zf.y, e3.y, acc[r][3]);
                    acc[r][3] = fmaf(zf.z, e3.z, acc[r][3]);
                    acc[r][3] = fmaf(zf.w, e3.w, acc[r][3]);
                }
            }
        }
        const float ck0 = cvec[c0], ck1 = cvec[c0 + 256];
        const float ck2 = cvec[c0 + 512], ck3 = cvec[c0 + 768];
#pragma unroll
        for (int r = 0; r < 16; ++r) {
            float d0 = __fadd_rn(__fsub_rn(sa[r], __fmul_rn(2.0f, acc[r][0])), ck0);
            float d1 = __fadd_rn(__fsub_rn(sa[r], __fmul_rn(2.0f, acc[r][1])), ck1);
            float d2 = __fadd_rn(__fsub_rn(sa[r], __fmul_rn(2.0f, acc[r][2])), ck2);
            float d3 = __fadd_rn(__fsub_rn(sa[r], __fmul_rn(2.0f, acc[r][3])), ck3);
            unsigned long long p0 = ((unsigned long long)__float_as_uint(d0) << 32) | (unsigned)(c0);
            unsigned long long p1 = ((unsigned long long)__float_as_uint(d1) << 32) | (unsigned)(c0 + 256);
            unsigned long long p2 = ((unsigned long long)__float_as_uint(d2) << 32) | (unsigned)(c0 + 512);
            unsigned long long p3 = ((unsigned long long)__float_as_uint(d3) << 32) | (unsigned)(c0 + 768);
            unsigned long long pa = p0 < p1 ? p0 : p1;
            unsigned long long pb = p2 < p3 ? p2 : p3;
            unsigned long long pm = pa < pb ? pa : pb;
            for (int msk = 32; msk >= 1; msk >>= 1) {
                unsigned long long qv = __shfl_xor(pm, msk);
                pm = qv < pm ? qv : pm;
            }
            if ((tid & 63) == 0) atomicMin(&rescored[srow[r]], pm);
        }
    }
}

// ---------------- writeback z_q_st + loss partials + fused index fixup ----------------
__global__ __launch_bounds__(256) void writeback_kernel(
        const float* __restrict__ z, const float* __restrict__ emb,
        const unsigned long long* __restrict__ rescored,
        float* __restrict__ out_idx, float* __restrict__ out0,
        double* __restrict__ partials) {
    const int tid = threadIdx.x;
    const int base = blockIdx.x * 32;
    double acc = 0.0;
    for (int g = 0; g < 8; ++g) {
        int row = base + g * 4 + (tid >> 6);
        int d4 = tid & 63;
        unsigned long long rv = rescored[row];
        int idx;
        if (rv != ~0ull) {                   // flagged: exact rescore wins
            idx = (int)(unsigned)(rv & 0xffffffffull);
            if (d4 == 0) out_idx[row] = (float)idx;
        } else {
            idx = (int)out_idx[row];
        }
        float4 q4 = *(const float4*)&emb[(size_t)idx * D_DIM + d4 * 4];
        float4 z4 = *(const float4*)&z[(size_t)row * D_DIM + d4 * 4];
        float4 o;
        float dx;
        dx = q4.x - z4.x; o.x = z4.x + dx; acc += (double)dx * dx;
        dx = q4.y - z4.y; o.y = z4.y + dx; acc += (double)dx * dx;
        dx = q4.z - z4.z; o.z = z4.z + dx; acc += (double)dx * dx;
        dx = q4.w - z4.w; o.w = z4.w + dx; acc += (double)dx * dx;
        *(float4*)&out0[(size_t)row * D_DIM + d4 * 4] = o;
    }
    for (int m = 32; m >= 1; m >>= 1) acc += __shfl_xor(acc, m);
    __shared__ double sd[4];
    if ((tid & 63) == 0) sd[tid >> 6] = acc;
    __syncthreads();
    if (tid == 0) partials[blockIdx.x] = (sd[0] + sd[1]) + (sd[2] + sd[3]);
}

__global__ void finalize_kernel(const double* __restrict__ partials, float* __restrict__ out_loss) {
    __shared__ double sd[256];
    const int tid = threadIdx.x;
    double a = 0.0;
    for (int i = tid; i < 2048; i += 256) a += partials[i];
    sd[tid] = a;
    __syncthreads();
    for (int s = 128; s > 0; s >>= 1) {
        if (tid < s) sd[tid] += sd[tid + s];
        __syncthreads();
    }
    if (tid == 0) {
        double m = sd[0] / 16777216.0;
        out_loss[0] = (float)(m + 0.25 * m);
    }
}

extern "C" void kernel_launch(void* const* d_in, const int* in_sizes, int n_in,
                              void* d_out, int out_size, void* d_ws, size_t ws_size,
                              hipStream_t stream) {
    const float* z = (const float*)d_in[0];
    const float* emb = (const float*)d_in[1];
    float* out0 = (float*)d_out;
    float* out_loss = out0 + (size_t)N_ROWS * D_DIM;
    float* out_idx = out_loss + 1;

    char* ws = (char*)d_ws;
    float* rownorm = (float*)ws;
    float* cvec = (float*)(ws + 262144);
    unsigned short* emb_perm = (unsigned short*)(ws + 278528);
    int* flagcnt = (int*)(ws + 2375680);
    int* flaglist = (int*)(ws + 2375936);
    unsigned long long* rescored = (unsigned long long*)(ws + 2638080);
    double* partials = (double*)(ws + 3162368);

    // 33.5 MB z_perm scratch inside d_out (fully overwritten by writeback_kernel)
    unsigned short* z_perm = (unsigned short*)d_out;

    cvt_emb_kernel<<<576, 256, 0, stream>>>(emb, emb_perm, cvec, flagcnt);          // +emb-norm +flagcnt clear
    cvt_z_kernel<<<9216, 256, 0, stream>>>(z, z_perm, rownorm, rescored);           // +z-norm +rescored clear
    phaseB_kernel<<<N_ROWS / 64, 256, 0, stream>>>(z_perm, emb_perm, cvec, out_idx, flagcnt, flaglist);
    rescore_kernel<<<1024, 256, 0, stream>>>(z, emb, rownorm, cvec, flagcnt, flaglist, rescored);
    writeback_kernel<<<N_ROWS / 32, 256, 0, stream>>>(z, emb, rescored, out_idx, out0, partials);
    finalize_kernel<<<1, 256, 0, stream>>>(partials, out_loss);
}

// Round 11
// 370.959 us; speedup vs baseline: 1.1105x; 1.1105x over previous
//
#include <hip/hip_runtime.h>

#define N_ROWS 65536
#define K_CODES 4096
#define D_DIM 256
#define MARGIN_BF 4.5e-5f

typedef __attribute__((ext_vector_type(8))) _Float16 f16x8;
typedef __attribute__((ext_vector_type(4))) float f32x4;

// ---------------- ws layout ----------------
// [0]        float  rownorm[65536]      256 KB
// [262144]   float  cvec[4096]           16 KB
// [278528]   ushort emb_perm[4096*256]    2 MB   (f16 x4096, B-frag stream-linear)
// [2375680]  int    flagcnt
// [2375936]  int    flaglist[65536]     256 KB
// [2638080]  u64    rescored[65536]     512 KB
// [3162368]  double partials[2048]       16 KB
// z_perm (33.5 MB, f16 fragment-linear) lives in d_out as scratch;
// writeback_kernel fully overwrites d_out afterwards (deterministic each replay).

union f16u { _Float16 h; unsigned short u; };

static __device__ __forceinline__ unsigned int pack2(float a, float b) {
    f16u x, y; x.h = (_Float16)a; y.h = (_Float16)b;
    return (unsigned)x.u | ((unsigned)y.u << 16);
}

// ---------------- r2-verified norm chain (verbatim body, block-offset) ----------------
static __device__ __forceinline__ void norm_body(const float* __restrict__ src,
                                                 float* __restrict__ dst, int bi, int tid) {
    int row = bi * 64 + (tid >> 2);
    int q = tid & 3;
    const float* p = src + (size_t)row * D_DIM;
    double acc = 0.0;
#pragma unroll 4
    for (int it = 0; it < 16; ++it) {
        float4 v = *(const float4*)&p[(q + 4 * it) * 4];
        float a = v.x * v.x, b = v.y * v.y, c = v.z * v.z, d = v.w * v.w;
        acc += (double)a; acc += (double)b; acc += (double)c; acc += (double)d;
    }
    acc += __shfl_xor(acc, 1);
    acc += __shfl_xor(acc, 2);
    if (q == 0) dst[row] = (float)acc;
}

// ---------------- emb -> f16(x4096), B-frag stream-linear  +  fused emb-norm ----------------
// frag f = ((h*64 + step)*8 + d8)*2 + cf  (2048 frags, 1KB each; linear per half h)
// lane part: holds emb[h*2048 + step*32 + cf*16 + (lane&15)][d8*32 + (lane>>4)*8 + 0..7] * 4096
__global__ __launch_bounds__(256) void cvt_emb_kernel(const float* __restrict__ emb,
                                                      unsigned short* __restrict__ emb_perm,
                                                      float* __restrict__ cvec,
                                                      int* __restrict__ flagcnt) {
    if (blockIdx.x >= 512) {
        if (blockIdx.x == 512 && threadIdx.x == 0) *flagcnt = 0;
        norm_body(emb, cvec, blockIdx.x - 512, threadIdx.x);
        return;
    }
    int gid = blockIdx.x * 256 + threadIdx.x;     // 131072 16B units
    int lane = gid & 63;
    int f = gid >> 6;
    int cf = f & 1;
    int d8 = (f >> 1) & 7;
    int step = (f >> 4) & 63;
    int h = f >> 10;
    int code = h * 2048 + step * 32 + cf * 16 + (lane & 15);
    int d0 = d8 * 32 + (lane >> 4) * 8;
    const float* p = emb + (size_t)code * D_DIM + d0;
    float4 v0 = *(const float4*)p;
    float4 v1 = *(const float4*)(p + 4);
    uint4 o;
    o.x = pack2(v0.x * 4096.0f, v0.y * 4096.0f);
    o.y = pack2(v0.z * 4096.0f, v0.w * 4096.0f);
    o.z = pack2(v1.x * 4096.0f, v1.y * 4096.0f);
    o.w = pack2(v1.z * 4096.0f, v1.w * 4096.0f);
    *(uint4*)((char*)emb_perm + (size_t)gid * 16) = o;
}

// ---------------- z -> f16 fragment-linear per 64-row group (r6-verified layout) ----------------
// ft = rg*2048 + (d8*4 + rf)*64 + lane ; holds z[rg*64 + rf*16 + (lane&15)][d8*32 + (lane>>4)*8 + 0..7]
__global__ __launch_bounds__(256) void cvt_z_kernel(const float* __restrict__ z,
                                                    unsigned short* __restrict__ z_perm,
                                                    float* __restrict__ rownorm,
                                                    unsigned long long* __restrict__ rescored) {
    if (blockIdx.x >= 8192) {
        norm_body(z, rownorm, blockIdx.x - 8192, threadIdx.x);
        return;
    }
    if (blockIdx.x < 256) rescored[blockIdx.x * 256 + threadIdx.x] = ~0ull;
    int ft = blockIdx.x * 256 + threadIdx.x;      // 2097152 frag-lanes
    int lane = ft & 63;
    int rf = (ft >> 6) & 3;
    int d8 = (ft >> 8) & 7;
    int rg = ft >> 11;
    int row = rg * 64 + rf * 16 + (lane & 15);
    int d0 = d8 * 32 + (lane >> 4) * 8;
    const float* p = z + (size_t)row * D_DIM + d0;
    float4 v0 = *(const float4*)p;
    float4 v1 = *(const float4*)(p + 4);
    uint4 o;
    o.x = pack2(v0.x, v0.y);
    o.y = pack2(v0.z, v0.w);
    o.z = pack2(v1.x, v1.y);
    o.w = pack2(v1.z, v1.w);
    *(uint4*)((char*)z_perm + (size_t)ft * 16) = o;
}

// ---------------- phase B: LDS-free B-streaming f16 MFMA argmin ----------------
// Block = 4 waves = 2 row-groups (pp: 64 rows, A in AGPRs) x 2 code-halves (h: 2048 codes).
// B frags stream global(L2)->VGPR in 4 rotating slots, depth-3 prefetch, linear addresses.
// No LDS in the K-loop (cvec served from a 16KB LDS table, lgkm path).
__global__ __launch_bounds__(256, 2) void phaseB_kernel(
        const unsigned short* __restrict__ z_perm, const unsigned short* __restrict__ emb_perm,
        const float* __restrict__ cvec, float* __restrict__ out_idx,
        int* __restrict__ flagcnt, int* __restrict__ flaglist) {
    __shared__ float cv[4096];     // 16 KB; reused as merge scratch after the loop

    const int tid = threadIdx.x;
    const int lane = tid & 63;
    const int w = tid >> 6;
    const int pp = w >> 1;         // row group
    const int h = w & 1;           // code half
    const int l15 = lane & 15, l4 = lane >> 4;
    const int rb = blockIdx.x;     // 512 blocks x 128 rows

    // ---- cvec -> LDS ----
#pragma unroll
    for (int i = 0; i < 4; ++i) {
        int idx = i * 1024 + tid * 4;
        *(float4*)&cv[idx] = *(const float4*)&cvec[idx];
    }

    // ---- A (64 rows) into registers (AGPR-eligible): 32 frags ----
    f16x8 A[8][4];
    {
        const char* zsrc = (const char*)z_perm + (size_t)(rb * 2 + pp) * 32768 + lane * 16;
#pragma unroll
        for (int d8 = 0; d8 < 8; ++d8)
#pragma unroll
            for (int rf = 0; rf < 4; ++rf)
                A[d8][rf] = *(const f16x8*)(zsrc + (d8 * 4 + rf) * 1024);
    }
    __syncthreads();               // cv ready

    // ---- B stream: pair p = (step*8 + d8); frag addr = base + p*2048 (+1024 for cf=1) ----
    const char* bq = (const char*)emb_perm + (size_t)h * 1048576 + lane * 16;

    f16x8 B0c0, B0c1, B1c0, B1c1, B2c0, B2c1, B3c0, B3c1;
    // prologue: slots 0..2 <- pairs 0..2
    B0c0 = *(const f16x8*)(bq);            B0c1 = *(const f16x8*)(bq + 1024);
    B1c0 = *(const f16x8*)(bq + 2048);     B1c1 = *(const f16x8*)(bq + 3072);
    B2c0 = *(const f16x8*)(bq + 4096);     B2c1 = *(const f16x8*)(bq + 5120);

    float m1[16], m2[16];
    int i1[16];
#pragma unroll
    for (int t = 0; t < 16; ++t) { m1[t] = 3.4e38f; m2[t] = 3.4e38f; i1[t] = 0; }

    f32x4 acc[4][2];

    for (int step = 0; step < 64; ++step) {
        const int kb = h * 2048 + step * 32;
        float ck0 = cv[kb + l15];
        float ck1 = cv[kb + 16 + l15];
#pragma unroll
        for (int rf = 0; rf < 4; ++rf) {
            acc[rf][0] = (f32x4){0.f, 0.f, 0.f, 0.f};
            acc[rf][1] = (f32x4){0.f, 0.f, 0.f, 0.f};
        }
        // 8 pairs; compute slot d8&3, prefetch pair d8+3 into slot (d8+3)&3.
        // Tail prefetches run past the half (or buffer end at h=1,step=63) into
        // mapped ws bytes -> garbage into dead regs, never consumed. Safe.
#pragma unroll
        for (int d8 = 0; d8 < 8; ++d8) {
            const char* pf = bq + (d8 + 3) * 2048;
            switch ((d8 + 3) & 3) {
                case 0: B0c0 = *(const f16x8*)pf; B0c1 = *(const f16x8*)(pf + 1024); break;
                case 1: B1c0 = *(const f16x8*)pf; B1c1 = *(const f16x8*)(pf + 1024); break;
                case 2: B2c0 = *(const f16x8*)pf; B2c1 = *(const f16x8*)(pf + 1024); break;
                default: B3c0 = *(const f16x8*)pf; B3c1 = *(const f16x8*)(pf + 1024); break;
            }
            f16x8 b0, b1;
            switch (d8 & 3) {
                case 0: b0 = B0c0; b1 = B0c1; break;
                case 1: b0 = B1c0; b1 = B1c1; break;
                case 2: b0 = B2c0; b1 = B2c1; break;
                default: b0 = B3c0; b1 = B3c1; break;
            }
#pragma unroll
            for (int rf = 0; rf < 4; ++rf) {
                acc[rf][0] = __builtin_amdgcn_mfma_f32_16x16x32_f16(A[d8][rf], b0, acc[rf][0], 0, 0, 0);
                acc[rf][1] = __builtin_amdgcn_mfma_f32_16x16x32_f16(A[d8][rf], b1, acc[rf][1], 0, 0, 0);
            }
        }
        bq += 16384;

        // ---- epilogue: top-2 over this step's 32 codes (numerics identical to r10) ----
#pragma unroll
        for (int cf = 0; cf < 2; ++cf) {
            float ck = cf ? ck1 : ck0;
            int codeg = kb + cf * 16 + l15;
#pragma unroll
            for (int rf = 0; rf < 4; ++rf)
#pragma unroll
                for (int j = 0; j < 4; ++j) {
                    // acc = z.(4096 e); -2*dot = acc * -2^-11 (exact scale)
                    float d = fmaf(-4.8828125e-4f, acc[rf][cf][j], ck);
                    const int t = rf * 4 + j;
                    bool lt = d < m1[t];
                    m2[t] = __builtin_amdgcn_fmed3f(d, m1[t], m2[t]);  // == min(m2,max(d,m1))
                    i1[t] = lt ? codeg : i1[t];
                    m1[t] = fminf(m1[t], d);
                }
        }
    }

    // ---- per-wave merge across the 16 column-lanes ----
    __syncthreads();               // cv (cvec) dead; reuse as merge scratch
    float* m1s = cv;               // [4][64]
    float* m2s = cv + 256;         // [4][64]
    int*   i1s = (int*)(cv + 512); // [4][64]
#pragma unroll
    for (int t = 0; t < 16; ++t) {
        float a1 = m1[t], a2 = m2[t];
        int ai = i1[t];
        for (int msk = 8; msk >= 1; msk >>= 1) {
            float b1 = __shfl_xor(a1, msk);
            float b2 = __shfl_xor(a2, msk);
            int   bi = __shfl_xor(ai, msk);
            float hi = fmaxf(a1, b1);
            a2 = fminf(fminf(a2, b2), hi);
            if (b1 < a1 || (b1 == a1 && bi < ai)) { a1 = b1; ai = bi; }
        }
        if (l15 == 0) {
            int rloc = (t >> 2) * 16 + l4 * 4 + (t & 3);   // row within the 64-row group
            m1s[w * 64 + rloc] = a1;
            m2s[w * 64 + rloc] = a2;
            i1s[w * 64 + rloc] = ai;
        }
    }
    __syncthreads();

    // ---- cross-wave merge: waves (2pp, 2pp+1) hold disjoint code halves ----
    if (tid < 128) {
        int pg = tid >> 6, r = tid & 63;
        float b1 = 3.4e38f, b2 = 3.4e38f;
        int bi = 0;
#pragma unroll
        for (int u = 0; u < 2; ++u) {
            int ww = pg * 2 + u;               // half 0 first -> first-index order kept
            float c1 = m1s[ww * 64 + r];
            float c2 = m2s[ww * 64 + r];
            int ci = i1s[ww * 64 + r];
            float hi2 = fmaxf(b1, c1);
            b2 = fminf(fminf(b2, c2), hi2);
            if (c1 < b1 || (c1 == b1 && ci < bi)) { b1 = c1; bi = ci; }
        }
        int rowg = rb * 128 + pg * 64 + r;
        out_idx[rowg] = (float)bi;
        if (b2 - b1 < MARGIN_BF) {
            int pz = atomicAdd(flagcnt, 1);
            flaglist[pz] = rowg;
        }
    }
}

// ---------------- exact f32 rescore: 4 codes/thread (chain bit-identical to r2) ----------------
__global__ __launch_bounds__(256) void rescore_kernel(
        const float* __restrict__ z, const float* __restrict__ emb,
        const float* __restrict__ rownorm, const float* __restrict__ cvec,
        const int* __restrict__ flagcnt, const int* __restrict__ flaglist,
        unsigned long long* __restrict__ rescored) {
    __shared__ float zs[16][256];
    __shared__ float sa[16];
    __shared__ int srow[16];
    const int tid = threadIdx.x;
    const int cnt = *flagcnt;
    const int nu = ((cnt + 15) >> 4) << 2;   // ceil(cnt/16) row-groups x 4 code-splits
    for (int uu = blockIdx.x; uu < nu; uu += gridDim.x) {
        int rg = uu >> 2, ks = uu & 3;
        __syncthreads();                      // previous unit done with zs/srow
        if (tid < 16) {
            int fi = rg * 16 + tid;
            int row = flaglist[fi < cnt ? fi : 0];   // padding = a real flagged row
            srow[tid] = row;
            sa[tid] = rownorm[row];
        }
        __syncthreads();
#pragma unroll
        for (int i = 0; i < 4; ++i) {
            int u = i * 256 + tid;            // 1024 float4 units
            int r = u >> 6, d4 = u & 63;
            *(float4*)&zs[r][d4 * 4] = *(const float4*)&z[(size_t)srow[r] * D_DIM + d4 * 4];
        }
        __syncthreads();

        const int c0 = ks * 1024 + tid;       // codes c0 + {0,256,512,768}
        float acc[16][4];
#pragma unroll
        for (int r = 0; r < 16; ++r)
#pragma unroll
            for (int j = 0; j < 4; ++j) acc[r][j] = 0.f;

        for (int ch = 0; ch < 8; ++ch) {      // 32 d per chunk, d ascending overall
#pragma unroll
            for (int q = 0; q < 8; ++q) {
                float4 e0 = *(const float4*)&emb[(size_t)(c0      ) * D_DIM + ch * 32 + q * 4];
                float4 e1 = *(const float4*)&emb[(size_t)(c0 + 256) * D_DIM + ch * 32 + q * 4];
                float4 e2 = *(const float4*)&emb[(size_t)(c0 + 512) * D_DIM + ch * 32 + q * 4];
                float4 e3 = *(const float4*)&emb[(size_t)(c0 + 768) * D_DIM + ch * 32 + q * 4];
#pragma unroll
                for (int r = 0; r < 16; ++r) {
                    float4 zf = *(const float4*)&zs[r][ch * 32 + q * 4];   // LDS broadcast
                    acc[r][0] = fmaf(zf.x, e0.x, acc[r][0]);
                    acc[r][0] = fmaf(zf.y, e0.y, acc[r][0]);
                    acc[r][0] = fmaf(zf.z, e0.z, acc[r][0]);
                    acc[r][0] = fmaf(zf.w, e0.w, acc[r][0]);
                    acc[r][1] = fmaf(zf.x, e1.x, acc[r][1]);
                    acc[r][1] = fmaf(zf.y, e1.y, acc[r][1]);
                    acc[r][1] = fmaf(zf.z, e1.z, acc[r][1]);
                    acc[r][1] = fmaf(zf.w, e1.w, acc[r][1]);
                    acc[r][2] = fmaf(zf.x, e2.x, acc[r][2]);
                    acc[r][2] = fmaf(zf.y, e2.y, acc[r][2]);
                    acc[r][2] = fmaf(zf.z, e2.z, acc[r][2]);
                    acc[r][2] = fmaf(zf.w, e2.w, acc[r][2]);
                    acc[r][3] = fmaf(zf.x, e3.x, acc[r][3]);
                    acc[r][3] = fmaf(zf.y, e3.y, acc[r][3]);
                    acc[r][3] = fmaf(zf.z, e3.z, acc[r][3]);
                    acc[r][3] = fmaf(zf.w, e3.w, acc[r][3]);
                }
            }
        }
        const float ck0 = cvec[c0], ck1 = cvec[c0 + 256];
        const float ck2 = cvec[c0 + 512], ck3 = cvec[c0 + 768];
#pragma unroll
        for (int r = 0; r < 16; ++r) {
            float d0 = __fadd_rn(__fsub_rn(sa[r], __fmul_rn(2.0f, acc[r][0])), ck0);
            float d1 = __fadd_rn(__fsub_rn(sa[r], __fmul_rn(2.0f, acc[r][1])), ck1);
            float d2 = __fadd_rn(__fsub_rn(sa[r], __fmul_rn(2.0f, acc[r][2])), ck2);
            float d3 = __fadd_rn(__fsub_rn(sa[r], __fmul_rn(2.0f, acc[r][3])), ck3);
            unsigned long long p0 = ((unsigned long long)__float_as_uint(d0) << 32) | (unsigned)(c0);
            unsigned long long p1 = ((unsigned long long)__float_as_uint(d1) << 32) | (unsigned)(c0 + 256);
            unsigned long long p2 = ((unsigned long long)__float_as_uint(d2) << 32) | (unsigned)(c0 + 512);
            unsigned long long p3 = ((unsigned long long)__float_as_uint(d3) << 32) | (unsigned)(c0 + 768);
            unsigned long long pa = p0 < p1 ? p0 : p1;
            unsigned long long pb = p2 < p3 ? p2 : p3;
            unsigned long long pm = pa < pb ? pa : pb;
            for (int msk = 32; msk >= 1; msk >>= 1) {
                unsigned long long qv = __shfl_xor(pm, msk);
                pm = qv < pm ? qv : pm;
            }
            if ((tid & 63) == 0) atomicMin(&rescored[srow[r]], pm);
        }
    }
}

// ---------------- writeback z_q_st + loss partials + fused index fixup ----------------
__global__ __launch_bounds__(256) void writeback_kernel(
        const float* __restrict__ z, const float* __restrict__ emb,
        const unsigned long long* __restrict__ rescored,
        float* __restrict__ out_idx, float* __restrict__ out0,
        double* __restrict__ partials) {
    const int tid = threadIdx.x;
    const int base = blockIdx.x * 32;
    double acc = 0.0;
    for (int g = 0; g < 8; ++g) {
        int row = base + g * 4 + (tid >> 6);
        int d4 = tid & 63;
        unsigned long long rv = rescored[row];
        int idx;
        if (rv != ~0ull) {                   // flagged: exact rescore wins
            idx = (int)(unsigned)(rv & 0xffffffffull);
            if (d4 == 0) out_idx[row] = (float)idx;
        } else {
            idx = (int)out_idx[row];
        }
        float4 q4 = *(const float4*)&emb[(size_t)idx * D_DIM + d4 * 4];
        float4 z4 = *(const float4*)&z[(size_t)row * D_DIM + d4 * 4];
        float4 o;
        float dx;
        dx = q4.x - z4.x; o.x = z4.x + dx; acc += (double)dx * dx;
        dx = q4.y - z4.y; o.y = z4.y + dx; acc += (double)dx * dx;
        dx = q4.z - z4.z; o.z = z4.z + dx; acc += (double)dx * dx;
        dx = q4.w - z4.w; o.w = z4.w + dx; acc += (double)dx * dx;
        *(float4*)&out0[(size_t)row * D_DIM + d4 * 4] = o;
    }
    for (int m = 32; m >= 1; m >>= 1) acc += __shfl_xor(acc, m);
    __shared__ double sd[4];
    if ((tid & 63) == 0) sd[tid >> 6] = acc;
    __syncthreads();
    if (tid == 0) partials[blockIdx.x] = (sd[0] + sd[1]) + (sd[2] + sd[3]);
}

__global__ void finalize_kernel(const double* __restrict__ partials, float* __restrict__ out_loss) {
    __shared__ double sd[256];
    const int tid = threadIdx.x;
    double a = 0.0;
    for (int i = tid; i < 2048; i += 256) a += partials[i];
    sd[tid] = a;
    __syncthreads();
    for (int s = 128; s > 0; s >>= 1) {
        if (tid < s) sd[tid] += sd[tid + s];
        __syncthreads();
    }
    if (tid == 0) {
        double m = sd[0] / 16777216.0;
        out_loss[0] = (float)(m + 0.25 * m);
    }
}

extern "C" void kernel_launch(void* const* d_in, const int* in_sizes, int n_in,
                              void* d_out, int out_size, void* d_ws, size_t ws_size,
                              hipStream_t stream) {
    const float* z = (const float*)d_in[0];
    const float* emb = (const float*)d_in[1];
    float* out0 = (float*)d_out;
    float* out_loss = out0 + (size_t)N_ROWS * D_DIM;
    float* out_idx = out_loss + 1;

    char* ws = (char*)d_ws;
    float* rownorm = (float*)ws;
    float* cvec = (float*)(ws + 262144);
    unsigned short* emb_perm = (unsigned short*)(ws + 278528);
    int* flagcnt = (int*)(ws + 2375680);
    int* flaglist = (int*)(ws + 2375936);
    unsigned long long* rescored = (unsigned long long*)(ws + 2638080);
    double* partials = (double*)(ws + 3162368);

    // 33.5 MB z_perm scratch inside d_out (fully overwritten by writeback_kernel)
    unsigned short* z_perm = (unsigned short*)d_out;

    cvt_emb_kernel<<<576, 256, 0, stream>>>(emb, emb_perm, cvec, flagcnt);      // +emb-norm +flagcnt clear
    cvt_z_kernel<<<9216, 256, 0, stream>>>(z, z_perm, rownorm, rescored);       // +z-norm +rescored clear
    phaseB_kernel<<<512, 256, 0, stream>>>(z_perm, emb_perm, cvec, out_idx, flagcnt, flaglist);
    rescore_kernel<<<1024, 256, 0, stream>>>(z, emb, rownorm, cvec, flagcnt, flaglist, rescored);
    writeback_kernel<<<N_ROWS / 32, 256, 0, stream>>>(z, emb, rescored, out_idx, out0, partials);
    finalize_kernel<<<1, 256, 0, stream>>>(partials, out_loss);
}